// Round 17
// baseline (309.393 us; speedup 1.0000x reference)
//
#include <hip/hip_runtime.h>
#include <hip/hip_bf16.h>

#define NR 4096

// ===== R17 attribution round: REP on prepG (x6) and gemm1 (x3) ONLY.
// true prepG = dur/6; true gemm1 = dur/3; also total = 75 + 5*prepG + 2*gemm1.
#define REP_PREP 6

typedef float f32x4 __attribute__((ext_vector_type(4)));
typedef __bf16 bf16x8 __attribute__((ext_vector_type(8)));

typedef __attribute__((address_space(1))) unsigned int u32_g;
typedef __attribute__((address_space(3))) unsigned int u32_l;

__device__ __forceinline__ void gl_lds16(const void* g, void* l) {
  __builtin_amdgcn_global_load_lds((const u32_g*)g, (u32_l*)l, 16, 0, 0);
}

// =====================================================================
// Staged operand layout (bf16): logical Z[rows][K], row-blocks RB of 256,
// K-tiles T of 64:  chunk(row,k) at
//   off = ((RB*KT + T)*2 + s)*16384 + g*4096 + (row&255)*16 + e*2
// B cols expert-interleaved: p = (o>>5)*256+((o>>3)&3)*64+(e>>1)*16+(o&7)*2+(e&1)
// =====================================================================

__device__ void wstage32(const float* __restrict__ w, __hip_bfloat16* __restrict__ out,
                         int Kin, int KT, int Oin, int u, char* LDS)
{
  int ob = u / (KT * 2);
  int rem = u - ob * (KT * 2);
  int T = rem >> 1, s = rem & 1;
  float* t = (float*)LDS;                    // [256][33]
  const int tid = threadIdx.x;
  const int kbase = T * 64 + s * 32;

  if (Oin == 512) {
#pragma unroll
    for (int i = 0; i < 8; ++i) {
      int idx = i * 256 + tid;
      int row = idx >> 3, c4 = idx & 7;
      int e = row >> 5, kk = row & 31;
      int k = kbase + kk;
      float4 v = {0.f, 0.f, 0.f, 0.f};
      if (k < Kin) v = *(const float4*)&w[((size_t)e * Kin + k) * 512 + ob * 32 + c4 * 4];
      t[row * 33 + c4 * 4 + 0] = v.x;
      t[row * 33 + c4 * 4 + 1] = v.y;
      t[row * 33 + c4 * 4 + 2] = v.z;
      t[row * 33 + c4 * 4 + 3] = v.w;
    }
  } else {
#pragma unroll
    for (int i = 0; i < 8; ++i) {
      int idx = i * 256 + tid;
      int row = idx >> 3, c4 = idx & 7;
      int e = row >> 5, kk = row & 31;
      int k = kbase + kk;
#pragma unroll
      for (int j = 0; j < 4; ++j) {
        int o = ob * 32 + c4 * 4 + j;
        float f = (k < Kin && o < Oin) ? w[((size_t)e * Kin + k) * (size_t)Oin + o] : 0.f;
        t[row * 33 + c4 * 4 + j] = f;
      }
    }
  }
  __syncthreads();
  {
    int p = tid;
    int e = ((p >> 4) & 3) * 2 + (p & 1);
    int oo = ((p >> 6) & 3) * 8 + ((p >> 1) & 7);
    size_t segbase = (((size_t)ob * KT + T) * 2 + s) * 16384;
#pragma unroll
    for (int g = 0; g < 4; ++g) {
      bf16x8 v;
#pragma unroll
      for (int e8 = 0; e8 < 8; ++e8) v[e8] = (__bf16)t[(e * 32 + g * 8 + e8) * 33 + oo];
      *(bf16x8*)((char*)out + segbase + g * 4096 + (size_t)p * 16) = v;
    }
  }
  __syncthreads();
}

__device__ void x0unit(int u, const float* __restrict__ cond, const float* __restrict__ lat,
                       __hip_bfloat16* __restrict__ out)
{
  int c = u * 256 + threadIdx.x;
  int RB = c / 10240;
  int r1 = c - RB * 10240;
  int T = r1 >> 11, r2 = r1 & 2047;
  int n = RB * 256 + (r2 & 255);
  int k0 = T * 64 + (r2 >> 10) * 32 + ((r2 >> 8) & 3) * 8;
  bf16x8 v;
#pragma unroll
  for (int e = 0; e < 8; ++e) {
    int k = k0 + e;
    float f = (k < 219) ? cond[(size_t)n * 219 + k]
            : (k < 283) ? lat[(size_t)n * 64 + (k - 219)] : 0.f;
    v[e] = (__bf16)f;
  }
  *(bf16x8*)((char*)out + (size_t)c * 16) = v;
}

__device__ void x1lat(int u, const float* __restrict__ lat, __hip_bfloat16* __restrict__ out)
{
  int c = u * 256 + threadIdx.x;
  int RB = c >> 11, r2 = c & 2047;
  int n = RB * 256 + (r2 & 255);
  int k0 = (r2 >> 10) * 32 + ((r2 >> 8) & 3) * 8;
  bf16x8 v;
#pragma unroll
  for (int e = 0; e < 8; ++e) v[e] = (__bf16)lat[(size_t)n * 64 + k0 + e];
  size_t off = ((size_t)RB * 9 + 8) * 32768 + (size_t)r2 * 16;
  *(bf16x8*)((char*)out + off) = v;
}

__device__ void gate16(int gb, const float* __restrict__ phs, const float* __restrict__ lat,
                       const float* __restrict__ gw1, const float* __restrict__ gb1,
                       const float* __restrict__ gw2, const float* __restrict__ gb2,
                       const float* __restrict__ gw3, const float* __restrict__ gb3,
                       float* __restrict__ coeff, char* LDS)
{
  float* aT  = (float*)LDS;
  float* h1T = (float*)(LDS + 10240);
  float* w3L = (float*)(LDS + 20480);
  const int tid = threadIdx.x;
  const int n0 = gb * 16;

  for (int i = tid; i < 104 * 16; i += 256) {
    int k = i >> 4, r = i & 15;
    aT[k * 20 + r] = (k < 40) ? phs[(size_t)(n0 + r) * 40 + k]
                              : lat[(size_t)(n0 + r) * 64 + (k - 40)];
  }
  ((float4*)w3L)[tid] = ((const float4*)gw3)[tid];
  __syncthreads();

  const int col = tid & 127, rh = tid >> 7;
  {
    float acc[8] = {};
#pragma unroll 8
    for (int k = 0; k < 104; ++k) {
      float w = gw1[k * 128 + col];
#pragma unroll
      for (int r = 0; r < 8; ++r) acc[r] += aT[k * 20 + rh * 8 + r] * w;
    }
    float bb = gb1[col];
#pragma unroll
    for (int r = 0; r < 8; ++r) {
      float v = acc[r] + bb;
      h1T[col * 20 + rh * 8 + r] = v > 0.f ? v : expm1f(v);
    }
  }
  __syncthreads();
  {
    float acc[8] = {};
#pragma unroll 8
    for (int k = 0; k < 128; ++k) {
      float w = gw2[k * 128 + col];
#pragma unroll
      for (int r = 0; r < 8; ++r) acc[r] += h1T[k * 20 + rh * 8 + r] * w;
    }
    float bb = gb2[col];
#pragma unroll
    for (int r = 0; r < 8; ++r) {
      float v = acc[r] + bb;
      aT[col * 20 + rh * 8 + r] = v > 0.f ? v : expm1f(v);
    }
  }
  __syncthreads();
  if (tid < 128) {
    int row = tid >> 3, e = tid & 7;
    float a3 = 0.f;
#pragma unroll 8
    for (int k = 0; k < 128; ++k) a3 += aT[k * 20 + row] * w3L[k * 8 + e];
    float lgt = a3 + gb3[e];
    float m = lgt;
    m = fmaxf(m, __shfl_xor(m, 1));
    m = fmaxf(m, __shfl_xor(m, 2));
    m = fmaxf(m, __shfl_xor(m, 4));
    float ex = expf(lgt - m);
    float s = ex;
    s += __shfl_xor(s, 1);
    s += __shfl_xor(s, 2);
    s += __shfl_xor(s, 4);
    coeff[(size_t)(n0 + row) * 8 + e] = ex / s;
  }
}

// ---- prepG with REP instrumentation ----
__global__ __launch_bounds__(256) void prepG(
    const float* __restrict__ latent, const float* __restrict__ condition,
    const float* __restrict__ phase,
    const float* __restrict__ gw1, const float* __restrict__ gb1,
    const float* __restrict__ gw2, const float* __restrict__ gb2,
    const float* __restrict__ gw3, const float* __restrict__ gb3,
    const float* __restrict__ w0, const float* __restrict__ w1, const float* __restrict__ w2,
    __hip_bfloat16* x0s, __hip_bfloat16* x1s,
    __hip_bfloat16* w0s, __hip_bfloat16* w1s, __hip_bfloat16* w2s,
    float* coeff)
{
  __shared__ __align__(16) char LDS[33792];
#pragma unroll 1
  for (int rep = 0; rep < REP_PREP; ++rep) {
    int b = blockIdx.x;
    if (b < 256) {
      gate16(b, phase, latent, gw1, gb1, gw2, gb2, gw3, gb3, coeff, LDS);
    } else {
      b -= 256;
      if (b < 288)       wstage32(w1, w1s, 576, 9, 512, b, LDS);
      else if (b < 448)  wstage32(w0, w0s, 283, 5, 512, b - 288, LDS);
      else if (b < 544)  wstage32(w2, w2s, 512, 8, 171, b - 448, LDS);
      else if (b < 1184) x0unit(b - 544, condition, latent, x0s);
      else {
        int u0 = (b - 1184) * 2;
        x1lat(u0, latent, x1s);
        x1lat(u0 + 1, latent, x1s);
      }
    }
    __syncthreads();
  }
}

// =====================================================================
// GEMM: 128x256 tile (R13-verified), template REP for attribution.
// =====================================================================
template <int KT, int KTD, int MODE, int BYPG, int REP>
__global__ __launch_bounds__(512, 4) void gemm_k(
    const __hip_bfloat16* __restrict__ Ap, const __hip_bfloat16* __restrict__ Bp,
    const float* __restrict__ coeff, const float* __restrict__ bias,
    __hip_bfloat16* __restrict__ dstS, float* __restrict__ dstF)
{
  __shared__ __align__(16) char lds[49152];
  const int bid = blockIdx.x;
  const int xcd = bid & 7, r = bid >> 3;
  const int bx = ((xcd & 3) << 3) + (r & 7);
  const int by = (xcd >> 2) * BYPG + (r >> 3);
  const int tid = threadIdx.x;
  const int lane = tid & 63;
  const int wid = tid >> 6;
  const int wr = wid >> 2, wc = wid & 3;
  const int l15 = lane & 15, lg = lane >> 4;
  const int aHalf = (bx & 1) * 2048;

  const char* aG = (const char*)Ap + (size_t)(bx >> 1) * KT * 32768;
  const char* bG = (const char*)Bp + (size_t)by * KT * 32768;

#define STAGE(T)                                                             \
  {                                                                          \
    const char* gA_ = aG + (size_t)(T) * 32768;                              \
    const char* gB_ = bG + (size_t)(T) * 32768;                              \
    _Pragma("unroll") for (int i = 0; i < 2; ++i) {                          \
      int c = i * 512 + tid;                                                 \
      gl_lds16(gA_ + (c >> 9) * 16384 + ((c >> 7) & 3) * 4096 + aHalf        \
                   + (c & 127) * 16,                                         \
               lds + c * 16);                                                \
    }                                                                        \
    _Pragma("unroll") for (int i = 0; i < 4; ++i) {                          \
      int c = i * 512 + tid;                                                 \
      gl_lds16(gB_ + c * 16, lds + 16384 + c * 16);                          \
    }                                                                        \
  }

#pragma unroll 1
  for (int rep = 0; rep < REP; ++rep) {
    f32x4 acc[4][4] = {};

    STAGE(0);
    asm volatile("s_waitcnt vmcnt(0)" ::: "memory");
    __builtin_amdgcn_s_barrier();

#pragma unroll 1
    for (int t = 0; t < KT; ++t) {
#pragma unroll
      for (int s = 0; s < 2; ++s) {
        bf16x8 a[4], b[4];
#pragma unroll
        for (int fm = 0; fm < 4; ++fm)
          a[fm] = *(const bf16x8*)(lds + s * 8192 + lg * 2048
                                   + ((wr << 6) + fm * 16 + l15) * 16);
#pragma unroll
        for (int nf = 0; nf < 4; ++nf)
          b[nf] = *(const bf16x8*)(lds + 16384 + s * 16384 + lg * 4096
                                   + (wc << 10) + nf * 256 + l15 * 16);
#pragma unroll
        for (int fm = 0; fm < 4; ++fm)
#pragma unroll
          for (int nf = 0; nf < 4; ++nf)
            acc[fm][nf] = __builtin_amdgcn_mfma_f32_16x16x32_bf16(a[fm], b[nf], acc[fm][nf], 0, 0, 0);
      }
      if (t + 1 < KT) {
        __builtin_amdgcn_s_barrier();
        STAGE(t + 1);
        asm volatile("s_waitcnt vmcnt(0)" ::: "memory");
        __builtin_amdgcn_s_barrier();
      }
    }
    __syncthreads();

    // fused expert-blend epilogue
    float* cl2 = (float*)lds;
    float* tb  = (float*)(lds + 4352);
    {
#pragma unroll
      for (int i = 0; i < 2; ++i) {
        int idx = i * 512 + tid;
        int e = idx & 7, n = idx >> 3;
        cl2[e * 132 + n] = coeff[((size_t)bx * 128 + n) * 8 + e];
      }
    }
    __syncthreads();
    const int e0 = lane & 1;
    const int o_loc = (wc << 3) + (l15 >> 1);

    if (MODE == 0) {
      float bb[4];
#pragma unroll
      for (int fn = 0; fn < 4; ++fn) bb[fn] = bias[(fn * 2 + e0) * 512 + by * 32 + o_loc];
#pragma unroll
      for (int fm = 0; fm < 4; ++fm) {
#pragma unroll
        for (int r2 = 0; r2 < 4; ++r2) {
          int n_loc = (wr << 6) + fm * 16 + (lg << 2) + r2;
          float s = 0.f;
#pragma unroll
          for (int fn = 0; fn < 4; ++fn)
            s += cl2[(fn * 2 + e0) * 132 + n_loc] * (acc[fm][fn][r2] + bb[fn]);
          s += __shfl_xor(s, 1);
          s = s > 0.f ? s : expm1f(s);
          if ((lane & 1) == (fm & 1)) tb[n_loc * 33 + o_loc] = s;
        }
      }
      __syncthreads();
      {
        int n_loc = tid & 127, c = tid >> 7;
        const float* p = &tb[n_loc * 33 + c * 8];
        bf16x8 v;
#pragma unroll
        for (int j = 0; j < 8; ++j) v[j] = (__bf16)p[j];
        size_t off = (((size_t)(bx >> 1) * KTD + (by >> 1)) * 2 + (by & 1)) * 16384
                   + (size_t)c * 4096 + (size_t)((bx & 1) * 128 + n_loc) * 16;
        *(bf16x8*)((char*)dstS + off) = v;
      }
    } else {
      const int o_g = by * 32 + o_loc;
      if (o_g < 171) {
        float bb[4];
#pragma unroll
        for (int fn = 0; fn < 4; ++fn) bb[fn] = bias[(fn * 2 + e0) * 171 + o_g];
#pragma unroll
        for (int fm = 0; fm < 4; ++fm) {
#pragma unroll
          for (int r2 = 0; r2 < 4; ++r2) {
            int n_loc = (wr << 6) + fm * 16 + (lg << 2) + r2;
            float s = 0.f;
#pragma unroll
            for (int fn = 0; fn < 4; ++fn)
              s += cl2[(fn * 2 + e0) * 132 + n_loc] * (acc[fm][fn][r2] + bb[fn]);
            s += __shfl_xor(s, 1);
            if ((lane & 1) == (fm & 1))
              dstF[(size_t)(bx * 128 + n_loc) * 171 + o_g] = s;
          }
        }
      }
    }
    __syncthreads();  // rep boundary
  }
#undef STAGE
}

// ---------------- launch ----------------
extern "C" void kernel_launch(void* const* d_in, const int* in_sizes, int n_in,
                              void* d_out, int out_size, void* d_ws, size_t ws_size,
                              hipStream_t stream)
{
  const float* latent    = (const float*)d_in[0];
  const float* condition = (const float*)d_in[1];
  const float* phase     = (const float*)d_in[2];
  const float* gw1 = (const float*)d_in[3];
  const float* gb1 = (const float*)d_in[4];
  const float* gw2 = (const float*)d_in[5];
  const float* gb2 = (const float*)d_in[6];
  const float* gw3 = (const float*)d_in[7];
  const float* gb3 = (const float*)d_in[8];
  const float* w0  = (const float*)d_in[9];
  const float* b0  = (const float*)d_in[10];
  const float* w1  = (const float*)d_in[11];
  const float* b1  = (const float*)d_in[12];
  const float* w2  = (const float*)d_in[13];
  const float* b2  = (const float*)d_in[14];

  float* out   = (float*)d_out;
  float* coeff = out + (size_t)NR * 171;

  char* ws = (char*)d_ws;
  __hip_bfloat16* x0s = (__hip_bfloat16*)ws; ws += (size_t)16 * 5 * 32768;
  __hip_bfloat16* x1s = (__hip_bfloat16*)ws; ws += (size_t)16 * 9 * 32768;
  __hip_bfloat16* x2s = (__hip_bfloat16*)ws; ws += (size_t)16 * 8 * 32768;
  __hip_bfloat16* w0s = (__hip_bfloat16*)ws; ws += (size_t)16 * 5 * 32768;
  __hip_bfloat16* w1s = (__hip_bfloat16*)ws; ws += (size_t)16 * 9 * 32768;
  __hip_bfloat16* w2s = (__hip_bfloat16*)ws; ws += (size_t)6 * 8 * 32768;

  // K1: prepG x6 (attribution)
  prepG<<<1504, 256, 0, stream>>>(latent, condition, phase,
                                  gw1, gb1, gw2, gb2, gw3, gb3,
                                  w0, w1, w2,
                                  x0s, x1s, w0s, w1s, w2s, coeff);

  // K2: gemm0 x1
  gemm_k<5, 9, 0, 8, 1><<<512, 512, 0, stream>>>(x0s, w0s, coeff, b0, x1s, nullptr);
  // K3: gemm1 x3 (attribution)
  gemm_k<9, 8, 0, 8, 3><<<512, 512, 0, stream>>>(x1s, w1s, coeff, b1, x2s, nullptr);
  // K4: gemm2 x1
  gemm_k<8, 0, 1, 3, 1><<<192, 512, 0, stream>>>(x2s, w2s, coeff, b2, nullptr, out);
}

// Round 18
// 83.067 us; speedup vs baseline: 3.7246x; 3.7246x over previous
//
#include <hip/hip_runtime.h>
#include <hip/hip_bf16.h>

#define NR 4096

typedef float f32x4 __attribute__((ext_vector_type(4)));
typedef __bf16 bf16x8 __attribute__((ext_vector_type(8)));

typedef __attribute__((address_space(1))) unsigned int u32_g;
typedef __attribute__((address_space(3))) unsigned int u32_l;

__device__ __forceinline__ void gl_lds16(const void* g, void* l) {
  __builtin_amdgcn_global_load_lds((const u32_g*)g, (u32_l*)l, 16, 0, 0);
}

// =====================================================================
// Staged operand layout (bf16): logical Z[rows][K], row-blocks RB of 256,
// K-tiles T of 64:  chunk(row,k) at
//   off = ((RB*KT + T)*2 + s)*16384 + g*4096 + (row&255)*16 + e*2
// B cols expert-interleaved: p = (o>>5)*256+((o>>3)&3)*64+(e>>1)*16+(o&7)*2+(e&1)
// =====================================================================

__device__ void wstage32(const float* __restrict__ w, __hip_bfloat16* __restrict__ out,
                         int Kin, int KT, int Oin, int u, char* LDS)
{
  int ob = u / (KT * 2);
  int rem = u - ob * (KT * 2);
  int T = rem >> 1, s = rem & 1;
  float* t = (float*)LDS;                    // [256][33]
  const int tid = threadIdx.x;
  const int kbase = T * 64 + s * 32;

  if (Oin == 512) {
#pragma unroll
    for (int i = 0; i < 8; ++i) {
      int idx = i * 256 + tid;
      int row = idx >> 3, c4 = idx & 7;
      int e = row >> 5, kk = row & 31;
      int k = kbase + kk;
      float4 v = {0.f, 0.f, 0.f, 0.f};
      if (k < Kin) v = *(const float4*)&w[((size_t)e * Kin + k) * 512 + ob * 32 + c4 * 4];
      t[row * 33 + c4 * 4 + 0] = v.x;
      t[row * 33 + c4 * 4 + 1] = v.y;
      t[row * 33 + c4 * 4 + 2] = v.z;
      t[row * 33 + c4 * 4 + 3] = v.w;
    }
  } else {
#pragma unroll
    for (int i = 0; i < 8; ++i) {
      int idx = i * 256 + tid;
      int row = idx >> 3, c4 = idx & 7;
      int e = row >> 5, kk = row & 31;
      int k = kbase + kk;
#pragma unroll
      for (int j = 0; j < 4; ++j) {
        int o = ob * 32 + c4 * 4 + j;
        float f = (k < Kin && o < Oin) ? w[((size_t)e * Kin + k) * (size_t)Oin + o] : 0.f;
        t[row * 33 + c4 * 4 + j] = f;
      }
    }
  }
  __syncthreads();
  {
    int p = tid;
    int e = ((p >> 4) & 3) * 2 + (p & 1);
    int oo = ((p >> 6) & 3) * 8 + ((p >> 1) & 7);
    size_t segbase = (((size_t)ob * KT + T) * 2 + s) * 16384;
#pragma unroll
    for (int g = 0; g < 4; ++g) {
      bf16x8 v;
#pragma unroll
      for (int e8 = 0; e8 < 8; ++e8) v[e8] = (__bf16)t[(e * 32 + g * 8 + e8) * 33 + oo];
      *(bf16x8*)((char*)out + segbase + g * 4096 + (size_t)p * 16) = v;
    }
  }
}

__device__ void x0unit(int u, const float* __restrict__ cond, const float* __restrict__ lat,
                       __hip_bfloat16* __restrict__ out)
{
  int c = u * 256 + threadIdx.x;
  int RB = c / 10240;
  int r1 = c - RB * 10240;
  int T = r1 >> 11, r2 = r1 & 2047;
  int n = RB * 256 + (r2 & 255);
  int k0 = T * 64 + (r2 >> 10) * 32 + ((r2 >> 8) & 3) * 8;
  bf16x8 v;
#pragma unroll
  for (int e = 0; e < 8; ++e) {
    int k = k0 + e;
    float f = (k < 219) ? cond[(size_t)n * 219 + k]
            : (k < 283) ? lat[(size_t)n * 64 + (k - 219)] : 0.f;
    v[e] = (__bf16)f;
  }
  *(bf16x8*)((char*)out + (size_t)c * 16) = v;
}

__device__ void x1lat(int u, const float* __restrict__ lat, __hip_bfloat16* __restrict__ out)
{
  int c = u * 256 + threadIdx.x;
  int RB = c >> 11, r2 = c & 2047;
  int n = RB * 256 + (r2 & 255);
  int k0 = (r2 >> 10) * 32 + ((r2 >> 8) & 3) * 8;
  bf16x8 v;
#pragma unroll
  for (int e = 0; e < 8; ++e) v[e] = (__bf16)lat[(size_t)n * 64 + k0 + e];
  size_t off = ((size_t)RB * 9 + 8) * 32768 + (size_t)r2 * 16;
  *(bf16x8*)((char*)out + off) = v;
}

// ---- stageK: staging ONLY (isolated from gate for the first time) ----
__global__ __launch_bounds__(256) void stageK(
    const float* __restrict__ latent, const float* __restrict__ condition,
    const float* __restrict__ w0, const float* __restrict__ w1, const float* __restrict__ w2,
    __hip_bfloat16* x0s, __hip_bfloat16* x1s,
    __hip_bfloat16* w0s, __hip_bfloat16* w1s, __hip_bfloat16* w2s)
{
  __shared__ __align__(16) char LDS[33792];
  int b = blockIdx.x;
  if (b < 288)       wstage32(w1, w1s, 576, 9, 512, b, LDS);
  else if (b < 448)  wstage32(w0, w0s, 283, 5, 512, b - 288, LDS);
  else if (b < 544)  wstage32(w2, w2s, 512, 8, 171, b - 448, LDS);
  else if (b < 1184) x0unit(b - 544, condition, latent, x0s);
  else {
    int u0 = (b - 1184) * 2;
    x1lat(u0, latent, x1s);
    x1lat(u0 + 1, latent, x1s);
  }
}

// ---- gateK v3: 1024 blocks x 128 threads x 4 rows -> 4 blocks/CU, 2 waves/SIMD ----
// Same k-ascending scalar accumulation chain per output -> bit-identical coeff.
__global__ __launch_bounds__(128) void gateK(
    const float* __restrict__ phs, const float* __restrict__ lat,
    const float* __restrict__ gw1, const float* __restrict__ gb1,
    const float* __restrict__ gw2, const float* __restrict__ gb2,
    const float* __restrict__ gw3, const float* __restrict__ gb3,
    float* __restrict__ coeff)
{
  __shared__ __align__(16) float aT[128 * 8];   // [k][4 rows + pad]
  __shared__ __align__(16) float h1T[128 * 8];
  __shared__ __align__(16) float w3L[128 * 8];
  const int tid = threadIdx.x;
  const int n0 = blockIdx.x * 4;

  for (int i = tid; i < 104 * 4; i += 128) {
    int k = i >> 2, r = i & 3;
    aT[k * 8 + r] = (k < 40) ? phs[(size_t)(n0 + r) * 40 + k]
                             : lat[(size_t)(n0 + r) * 64 + (k - 40)];
  }
#pragma unroll
  for (int i = 0; i < 2; ++i) ((float4*)w3L)[i * 128 + tid] = ((const float4*)gw3)[i * 128 + tid];
  __syncthreads();

  // layer 1: col = tid, 4 rows
  {
    float acc[4] = {};
#pragma unroll 8
    for (int k = 0; k < 104; ++k) {
      float w = gw1[k * 128 + tid];
#pragma unroll
      for (int r = 0; r < 4; ++r) acc[r] += aT[k * 8 + r] * w;
    }
    float bb = gb1[tid];
#pragma unroll
    for (int r = 0; r < 4; ++r) {
      float v = acc[r] + bb;
      h1T[tid * 8 + r] = v > 0.f ? v : expm1f(v);
    }
  }
  __syncthreads();
  // layer 2
  {
    float acc[4] = {};
#pragma unroll 8
    for (int k = 0; k < 128; ++k) {
      float w = gw2[k * 128 + tid];
#pragma unroll
      for (int r = 0; r < 4; ++r) acc[r] += h1T[k * 8 + r] * w;
    }
    float bb = gb2[tid];
#pragma unroll
    for (int r = 0; r < 4; ++r) {
      float v = acc[r] + bb;
      aT[tid * 8 + r] = v > 0.f ? v : expm1f(v);
    }
  }
  __syncthreads();
  // layer 3 + softmax (lanes 0..31: row=tid>>3, e=tid&7)
  if (tid < 32) {
    int row = tid >> 3, e = tid & 7;
    float a3 = 0.f;
#pragma unroll 8
    for (int k = 0; k < 128; ++k) a3 += aT[k * 8 + row] * w3L[k * 8 + e];
    float lgt = a3 + gb3[e];
    float m = lgt;
    m = fmaxf(m, __shfl_xor(m, 1));
    m = fmaxf(m, __shfl_xor(m, 2));
    m = fmaxf(m, __shfl_xor(m, 4));
    float ex = expf(lgt - m);
    float s = ex;
    s += __shfl_xor(s, 1);
    s += __shfl_xor(s, 2);
    s += __shfl_xor(s, 4);
    coeff[(size_t)(n0 + row) * 8 + e] = ex / s;
  }
}

// =====================================================================
// GEMM: 128x256 tile, 48KB LDS single-buffer, 2 blocks/CU, rectangular
// per-XCD tile mapping (R13-verified). MODE 0 -> staged bf16; 1 -> fp32.
// =====================================================================
template <int KT, int KTD, int MODE, int BYPG>
__global__ __launch_bounds__(512, 4) void gemm_k(
    const __hip_bfloat16* __restrict__ Ap, const __hip_bfloat16* __restrict__ Bp,
    const float* __restrict__ coeff, const float* __restrict__ bias,
    __hip_bfloat16* __restrict__ dstS, float* __restrict__ dstF)
{
  __shared__ __align__(16) char lds[49152];
  const int bid = blockIdx.x;
  const int xcd = bid & 7, r = bid >> 3;
  const int bx = ((xcd & 3) << 3) + (r & 7);
  const int by = (xcd >> 2) * BYPG + (r >> 3);
  const int tid = threadIdx.x;
  const int lane = tid & 63;
  const int wid = tid >> 6;
  const int wr = wid >> 2, wc = wid & 3;
  const int l15 = lane & 15, lg = lane >> 4;
  const int aHalf = (bx & 1) * 2048;

  const char* aG = (const char*)Ap + (size_t)(bx >> 1) * KT * 32768;
  const char* bG = (const char*)Bp + (size_t)by * KT * 32768;

#define STAGE(T)                                                             \
  {                                                                          \
    const char* gA_ = aG + (size_t)(T) * 32768;                              \
    const char* gB_ = bG + (size_t)(T) * 32768;                              \
    _Pragma("unroll") for (int i = 0; i < 2; ++i) {                          \
      int c = i * 512 + tid;                                                 \
      gl_lds16(gA_ + (c >> 9) * 16384 + ((c >> 7) & 3) * 4096 + aHalf        \
                   + (c & 127) * 16,                                         \
               lds + c * 16);                                                \
    }                                                                        \
    _Pragma("unroll") for (int i = 0; i < 4; ++i) {                          \
      int c = i * 512 + tid;                                                 \
      gl_lds16(gB_ + c * 16, lds + 16384 + c * 16);                          \
    }                                                                        \
  }

  f32x4 acc[4][4] = {};

  STAGE(0);
  asm volatile("s_waitcnt vmcnt(0)" ::: "memory");
  __builtin_amdgcn_s_barrier();

#pragma unroll 1
  for (int t = 0; t < KT; ++t) {
#pragma unroll
    for (int s = 0; s < 2; ++s) {
      bf16x8 a[4], b[4];
#pragma unroll
      for (int fm = 0; fm < 4; ++fm)
        a[fm] = *(const bf16x8*)(lds + s * 8192 + lg * 2048
                                 + ((wr << 6) + fm * 16 + l15) * 16);
#pragma unroll
      for (int nf = 0; nf < 4; ++nf)
        b[nf] = *(const bf16x8*)(lds + 16384 + s * 16384 + lg * 4096
                                 + (wc << 10) + nf * 256 + l15 * 16);
#pragma unroll
      for (int fm = 0; fm < 4; ++fm)
#pragma unroll
        for (int nf = 0; nf < 4; ++nf)
          acc[fm][nf] = __builtin_amdgcn_mfma_f32_16x16x32_bf16(a[fm], b[nf], acc[fm][nf], 0, 0, 0);
    }
    if (t + 1 < KT) {
      __builtin_amdgcn_s_barrier();
      STAGE(t + 1);
      asm volatile("s_waitcnt vmcnt(0)" ::: "memory");
      __builtin_amdgcn_s_barrier();
    }
  }
#undef STAGE
  __syncthreads();

  // fused expert-blend epilogue (coeff transposed [8][132]: conflict-free)
  float* cl2 = (float*)lds;
  float* tb  = (float*)(lds + 4352);
  {
#pragma unroll
    for (int i = 0; i < 2; ++i) {
      int idx = i * 512 + tid;
      int e = idx & 7, n = idx >> 3;
      cl2[e * 132 + n] = coeff[((size_t)bx * 128 + n) * 8 + e];
    }
  }
  __syncthreads();
  const int e0 = lane & 1;
  const int o_loc = (wc << 3) + (l15 >> 1);

  if (MODE == 0) {
    float bb[4];
#pragma unroll
    for (int fn = 0; fn < 4; ++fn) bb[fn] = bias[(fn * 2 + e0) * 512 + by * 32 + o_loc];
#pragma unroll
    for (int fm = 0; fm < 4; ++fm) {
#pragma unroll
      for (int r2 = 0; r2 < 4; ++r2) {
        int n_loc = (wr << 6) + fm * 16 + (lg << 2) + r2;
        float s = 0.f;
#pragma unroll
        for (int fn = 0; fn < 4; ++fn)
          s += cl2[(fn * 2 + e0) * 132 + n_loc] * (acc[fm][fn][r2] + bb[fn]);
        s += __shfl_xor(s, 1);
        s = s > 0.f ? s : expm1f(s);
        if ((lane & 1) == (fm & 1)) tb[n_loc * 33 + o_loc] = s;
      }
    }
    __syncthreads();
    {
      int n_loc = tid & 127, c = tid >> 7;
      const float* p = &tb[n_loc * 33 + c * 8];
      bf16x8 v;
#pragma unroll
      for (int j = 0; j < 8; ++j) v[j] = (__bf16)p[j];
      size_t off = (((size_t)(bx >> 1) * KTD + (by >> 1)) * 2 + (by & 1)) * 16384
                 + (size_t)c * 4096 + (size_t)((bx & 1) * 128 + n_loc) * 16;
      *(bf16x8*)((char*)dstS + off) = v;
    }
  } else {
    const int o_g = by * 32 + o_loc;
    if (o_g < 171) {
      float bb[4];
#pragma unroll
      for (int fn = 0; fn < 4; ++fn) bb[fn] = bias[(fn * 2 + e0) * 171 + o_g];
#pragma unroll
      for (int fm = 0; fm < 4; ++fm) {
#pragma unroll
        for (int r2 = 0; r2 < 4; ++r2) {
          int n_loc = (wr << 6) + fm * 16 + (lg << 2) + r2;
          float s = 0.f;
#pragma unroll
          for (int fn = 0; fn < 4; ++fn)
            s += cl2[(fn * 2 + e0) * 132 + n_loc] * (acc[fm][fn][r2] + bb[fn]);
          s += __shfl_xor(s, 1);
          if ((lane & 1) == (fm & 1))
            dstF[(size_t)(bx * 128 + n_loc) * 171 + o_g] = s;
        }
      }
    }
  }
}

// ---------------- launch ----------------
extern "C" void kernel_launch(void* const* d_in, const int* in_sizes, int n_in,
                              void* d_out, int out_size, void* d_ws, size_t ws_size,
                              hipStream_t stream)
{
  const float* latent    = (const float*)d_in[0];
  const float* condition = (const float*)d_in[1];
  const float* phase     = (const float*)d_in[2];
  const float* gw1 = (const float*)d_in[3];
  const float* gb1 = (const float*)d_in[4];
  const float* gw2 = (const float*)d_in[5];
  const float* gb2 = (const float*)d_in[6];
  const float* gw3 = (const float*)d_in[7];
  const float* gb3 = (const float*)d_in[8];
  const float* w0  = (const float*)d_in[9];
  const float* b0  = (const float*)d_in[10];
  const float* w1  = (const float*)d_in[11];
  const float* b1  = (const float*)d_in[12];
  const float* w2  = (const float*)d_in[13];
  const float* b2  = (const float*)d_in[14];

  float* out   = (float*)d_out;
  float* coeff = out + (size_t)NR * 171;

  char* ws = (char*)d_ws;
  __hip_bfloat16* x0s = (__hip_bfloat16*)ws; ws += (size_t)16 * 5 * 32768;
  __hip_bfloat16* x1s = (__hip_bfloat16*)ws; ws += (size_t)16 * 9 * 32768;
  __hip_bfloat16* x2s = (__hip_bfloat16*)ws; ws += (size_t)16 * 8 * 32768;
  __hip_bfloat16* w0s = (__hip_bfloat16*)ws; ws += (size_t)16 * 5 * 32768;
  __hip_bfloat16* w1s = (__hip_bfloat16*)ws; ws += (size_t)16 * 9 * 32768;
  __hip_bfloat16* w2s = (__hip_bfloat16*)ws; ws += (size_t)6 * 8 * 32768;

  // K1: staging only (1248 blocks) — first direct isolation of staging cost
  stageK<<<1248, 256, 0, stream>>>(latent, condition, w0, w1, w2,
                                   x0s, x1s, w0s, w1s, w2s);

  // K2: gate only — 1024 blocks x 128 thr x 4 rows (4 blocks/CU latency hiding)
  gateK<<<1024, 128, 0, stream>>>(phase, latent, gw1, gb1, gw2, gb2, gw3, gb3, coeff);

  // K3-K5: 128x256-tile fused GEMMs, rectangular XCD-L2 tile mapping
  gemm_k<5, 9, 0, 8><<<512, 512, 0, stream>>>(x0s, w0s, coeff, b0, x1s, nullptr);
  gemm_k<9, 8, 0, 8><<<512, 512, 0, stream>>>(x1s, w1s, coeff, b1, x2s, nullptr);
  gemm_k<8, 0, 1, 3><<<192, 512, 0, stream>>>(x2s, w2s, coeff, b2, nullptr, out);
}

// Round 19
// 72.746 us; speedup vs baseline: 4.2531x; 1.1419x over previous
//
#include <hip/hip_runtime.h>
#include <hip/hip_bf16.h>

#define NR 4096

typedef float f32x4 __attribute__((ext_vector_type(4)));
typedef __bf16 bf16x8 __attribute__((ext_vector_type(8)));

typedef __attribute__((address_space(1))) unsigned int u32_g;
typedef __attribute__((address_space(3))) unsigned int u32_l;

__device__ __forceinline__ void gl_lds16(const void* g, void* l) {
  __builtin_amdgcn_global_load_lds((const u32_g*)g, (u32_l*)l, 16, 0, 0);
}

// =====================================================================
// Staged operand layout (bf16): logical Z[rows][K], row-blocks RB of 256,
// K-tiles T of 64:  chunk(row,k) at
//   off = ((RB*KT + T)*2 + s)*16384 + g*4096 + (row&255)*16 + e*2
// B cols expert-interleaved: p = (o>>5)*256+((o>>3)&3)*64+(e>>1)*16+(o&7)*2+(e&1)
// =====================================================================

// ---- w-stager (R16-verified): coalesced loads + 4x4KB contiguous stores ----
__device__ void wstage32(const float* __restrict__ w, __hip_bfloat16* __restrict__ out,
                         int Kin, int KT, int Oin, int u, char* LDS)
{
  int ob = u / (KT * 2);
  int rem = u - ob * (KT * 2);
  int T = rem >> 1, s = rem & 1;
  float* t = (float*)LDS;                    // [256][33]
  const int tid = threadIdx.x;
  const int kbase = T * 64 + s * 32;

  if (Oin == 512) {
#pragma unroll
    for (int i = 0; i < 8; ++i) {
      int idx = i * 256 + tid;
      int row = idx >> 3, c4 = idx & 7;
      int e = row >> 5, kk = row & 31;
      int k = kbase + kk;
      float4 v = {0.f, 0.f, 0.f, 0.f};
      if (k < Kin) v = *(const float4*)&w[((size_t)e * Kin + k) * 512 + ob * 32 + c4 * 4];
      t[row * 33 + c4 * 4 + 0] = v.x;
      t[row * 33 + c4 * 4 + 1] = v.y;
      t[row * 33 + c4 * 4 + 2] = v.z;
      t[row * 33 + c4 * 4 + 3] = v.w;
    }
  } else {
#pragma unroll
    for (int i = 0; i < 8; ++i) {
      int idx = i * 256 + tid;
      int row = idx >> 3, c4 = idx & 7;
      int e = row >> 5, kk = row & 31;
      int k = kbase + kk;
#pragma unroll
      for (int j = 0; j < 4; ++j) {
        int o = ob * 32 + c4 * 4 + j;
        float f = (k < Kin && o < Oin) ? w[((size_t)e * Kin + k) * (size_t)Oin + o] : 0.f;
        t[row * 33 + c4 * 4 + j] = f;
      }
    }
  }
  __syncthreads();
  {
    int p = tid;
    int e = ((p >> 4) & 3) * 2 + (p & 1);
    int oo = ((p >> 6) & 3) * 8 + ((p >> 1) & 7);
    size_t segbase = (((size_t)ob * KT + T) * 2 + s) * 16384;
#pragma unroll
    for (int g = 0; g < 4; ++g) {
      bf16x8 v;
#pragma unroll
      for (int e8 = 0; e8 < 8; ++e8) v[e8] = (__bf16)t[(e * 32 + g * 8 + e8) * 33 + oo];
      *(bf16x8*)((char*)out + segbase + g * 4096 + (size_t)p * 16) = v;
    }
  }
}

// ---- x0 stager v2: COALESCED. Block = 32 rows; flat row copy -> LDS -> chunks ----
__device__ void x0stage32(int u, const float* __restrict__ cond, const float* __restrict__ lat,
                          __hip_bfloat16* __restrict__ out, char* LDS)
{
  float* Lc = (float*)LDS;            // [32][221] f32 (odd pitch: conflict-free)
  float* Ll = (float*)(LDS + 28288);  // [32][65] f32
  const int tid = threadIdx.x;
  const int n0 = u * 32;

  for (int i = tid; i < 32 * 219; i += 256) {      // flat coalesced read of cond rows
    int r = i / 219, c = i - r * 219;
    Lc[r * 221 + c] = cond[(size_t)n0 * 219 + i];
  }
  for (int i = tid; i < 32 * 64; i += 256) {       // flat coalesced read of latent rows
    int r = i >> 6, c = i & 63;
    Ll[r * 65 + c] = lat[(size_t)n0 * 64 + i];
  }
  __syncthreads();

  const int RB = u >> 3;
  const int rbase = (u & 7) * 32;
#pragma unroll
  for (int ii = 0; ii < 5; ++ii) {
    int cc = ii * 256 + tid;                       // 1280 chunks: kc*32 + row
    int row = cc & 31, kc = cc >> 5;               // kc in 0..39
    int T = kc >> 3, s = (kc >> 2) & 1, g = kc & 3;
    bf16x8 v;
#pragma unroll
    for (int j = 0; j < 8; ++j) {
      int k = kc * 8 + j;
      float f = (k < 219) ? Lc[row * 221 + k]
              : (k < 283) ? Ll[row * 65 + (k - 219)] : 0.f;
      v[j] = (__bf16)f;
    }
    size_t off = (((size_t)RB * 5 + T) * 2 + s) * 16384 + (size_t)g * 4096
               + (size_t)(rbase + row) * 16;
    *(bf16x8*)((char*)out + off) = v;
  }
}

// ---- x1 latent stager v2: COALESCED. Block = 64 rows ----
__device__ void x1stage64(int u, const float* __restrict__ lat,
                          __hip_bfloat16* __restrict__ out, char* LDS)
{
  float* L = (float*)LDS;  // [64][65] f32
  const int tid = threadIdx.x;
  const int n0 = u * 64;
  for (int i = tid; i < 64 * 64; i += 256) {
    int r = i >> 6, c = i & 63;
    L[r * 65 + c] = lat[(size_t)n0 * 64 + i];
  }
  __syncthreads();
  const int RB = u >> 2;
  const int rbase = (u & 3) * 64;
#pragma unroll
  for (int ii = 0; ii < 2; ++ii) {
    int cc = ii * 256 + tid;                       // 512 chunks: kc*64 + row
    int row = cc & 63, kc = cc >> 6;               // kc in 0..7
    int s = kc >> 2, g = kc & 3;
    bf16x8 v;
#pragma unroll
    for (int j = 0; j < 8; ++j) v[j] = (__bf16)L[row * 65 + kc * 8 + j];
    size_t off = ((size_t)RB * 9 + 8) * 32768
               + (size_t)((s << 10) | (g << 8) | (rbase + row)) * 16;
    *(bf16x8*)((char*)out + off) = v;
  }
}

// ---- compact gate (R15/R16-verified): 16 rows/block, pipelined loads ----
__device__ void gate16(int gb, const float* __restrict__ phs, const float* __restrict__ lat,
                       const float* __restrict__ gw1, const float* __restrict__ gb1,
                       const float* __restrict__ gw2, const float* __restrict__ gb2,
                       const float* __restrict__ gw3, const float* __restrict__ gb3,
                       float* __restrict__ coeff, char* LDS)
{
  float* aT  = (float*)LDS;            // [128][20]
  float* h1T = (float*)(LDS + 10240);  // [128][20]
  float* w3L = (float*)(LDS + 20480);  // [128][8]
  const int tid = threadIdx.x;
  const int n0 = gb * 16;

  for (int i = tid; i < 104 * 16; i += 256) {
    int k = i >> 4, r = i & 15;
    aT[k * 20 + r] = (k < 40) ? phs[(size_t)(n0 + r) * 40 + k]
                              : lat[(size_t)(n0 + r) * 64 + (k - 40)];
  }
  ((float4*)w3L)[tid] = ((const float4*)gw3)[tid];
  __syncthreads();

  const int col = tid & 127, rh = tid >> 7;
  {
    float acc[8] = {};
#pragma unroll 8
    for (int k = 0; k < 104; ++k) {
      float w = gw1[k * 128 + col];
#pragma unroll
      for (int r = 0; r < 8; ++r) acc[r] += aT[k * 20 + rh * 8 + r] * w;
    }
    float bb = gb1[col];
#pragma unroll
    for (int r = 0; r < 8; ++r) {
      float v = acc[r] + bb;
      h1T[col * 20 + rh * 8 + r] = v > 0.f ? v : expm1f(v);
    }
  }
  __syncthreads();
  {
    float acc[8] = {};
#pragma unroll 8
    for (int k = 0; k < 128; ++k) {
      float w = gw2[k * 128 + col];
#pragma unroll
      for (int r = 0; r < 8; ++r) acc[r] += h1T[k * 20 + rh * 8 + r] * w;
    }
    float bb = gb2[col];
#pragma unroll
    for (int r = 0; r < 8; ++r) {
      float v = acc[r] + bb;
      aT[col * 20 + rh * 8 + r] = v > 0.f ? v : expm1f(v);
    }
  }
  __syncthreads();
  if (tid < 128) {
    int row = tid >> 3, e = tid & 7;
    float a3 = 0.f;
#pragma unroll 8
    for (int k = 0; k < 128; ++k) a3 += aT[k * 20 + row] * w3L[k * 8 + e];
    float lgt = a3 + gb3[e];
    float m = lgt;
    m = fmaxf(m, __shfl_xor(m, 1));
    m = fmaxf(m, __shfl_xor(m, 2));
    m = fmaxf(m, __shfl_xor(m, 4));
    float ex = expf(lgt - m);
    float s = ex;
    s += __shfl_xor(s, 1);
    s += __shfl_xor(s, 2);
    s += __shfl_xor(s, 4);
    coeff[(size_t)(n0 + row) * 8 + e] = ex / s;
  }
}

// ---- prepG: gate first + all staging, fused (R16 structure, new x stagers) ----
__global__ __launch_bounds__(256) void prepG(
    const float* __restrict__ latent, const float* __restrict__ condition,
    const float* __restrict__ phase,
    const float* __restrict__ gw1, const float* __restrict__ gb1,
    const float* __restrict__ gw2, const float* __restrict__ gb2,
    const float* __restrict__ gw3, const float* __restrict__ gb3,
    const float* __restrict__ w0, const float* __restrict__ w1, const float* __restrict__ w2,
    __hip_bfloat16* x0s, __hip_bfloat16* x1s,
    __hip_bfloat16* w0s, __hip_bfloat16* w1s, __hip_bfloat16* w2s,
    float* coeff)
{
  __shared__ __align__(16) char LDS[36864];
  int b = blockIdx.x;
  if (b < 256) {
    gate16(b, phase, latent, gw1, gb1, gw2, gb2, gw3, gb3, coeff, LDS);
    return;
  }
  b -= 256;
  if (b < 288)       wstage32(w1, w1s, 576, 9, 512, b, LDS);         // 288
  else if (b < 448)  wstage32(w0, w0s, 283, 5, 512, b - 288, LDS);   // 160
  else if (b < 544)  wstage32(w2, w2s, 512, 8, 171, b - 448, LDS);   // 96
  else if (b < 672)  x0stage32(b - 544, condition, latent, x0s, LDS);// 128
  else               x1stage64(b - 672, latent, x1s, LDS);           // 64
}

// =====================================================================
// GEMM: 128x256 tile, 48KB LDS single-buffer, 2 blocks/CU, rectangular
// per-XCD tile mapping (R13-verified). MODE 0 -> staged bf16; 1 -> fp32.
// =====================================================================
template <int KT, int KTD, int MODE, int BYPG>
__global__ __launch_bounds__(512, 4) void gemm_k(
    const __hip_bfloat16* __restrict__ Ap, const __hip_bfloat16* __restrict__ Bp,
    const float* __restrict__ coeff, const float* __restrict__ bias,
    __hip_bfloat16* __restrict__ dstS, float* __restrict__ dstF)
{
  __shared__ __align__(16) char lds[49152];
  const int bid = blockIdx.x;
  const int xcd = bid & 7, r = bid >> 3;
  const int bx = ((xcd & 3) << 3) + (r & 7);
  const int by = (xcd >> 2) * BYPG + (r >> 3);
  const int tid = threadIdx.x;
  const int lane = tid & 63;
  const int wid = tid >> 6;
  const int wr = wid >> 2, wc = wid & 3;
  const int l15 = lane & 15, lg = lane >> 4;
  const int aHalf = (bx & 1) * 2048;

  const char* aG = (const char*)Ap + (size_t)(bx >> 1) * KT * 32768;
  const char* bG = (const char*)Bp + (size_t)by * KT * 32768;

#define STAGE(T)                                                             \
  {                                                                          \
    const char* gA_ = aG + (size_t)(T) * 32768;                              \
    const char* gB_ = bG + (size_t)(T) * 32768;                              \
    _Pragma("unroll") for (int i = 0; i < 2; ++i) {                          \
      int c = i * 512 + tid;                                                 \
      gl_lds16(gA_ + (c >> 9) * 16384 + ((c >> 7) & 3) * 4096 + aHalf        \
                   + (c & 127) * 16,                                         \
               lds + c * 16);                                                \
    }                                                                        \
    _Pragma("unroll") for (int i = 0; i < 4; ++i) {                          \
      int c = i * 512 + tid;                                                 \
      gl_lds16(gB_ + c * 16, lds + 16384 + c * 16);                          \
    }                                                                        \
  }

  f32x4 acc[4][4] = {};

  STAGE(0);
  asm volatile("s_waitcnt vmcnt(0)" ::: "memory");
  __builtin_amdgcn_s_barrier();

#pragma unroll 1
  for (int t = 0; t < KT; ++t) {
#pragma unroll
    for (int s = 0; s < 2; ++s) {
      bf16x8 a[4], b[4];
#pragma unroll
      for (int fm = 0; fm < 4; ++fm)
        a[fm] = *(const bf16x8*)(lds + s * 8192 + lg * 2048
                                 + ((wr << 6) + fm * 16 + l15) * 16);
#pragma unroll
      for (int nf = 0; nf < 4; ++nf)
        b[nf] = *(const bf16x8*)(lds + 16384 + s * 16384 + lg * 4096
                                 + (wc << 10) + nf * 256 + l15 * 16);
#pragma unroll
      for (int fm = 0; fm < 4; ++fm)
#pragma unroll
        for (int nf = 0; nf < 4; ++nf)
          acc[fm][nf] = __builtin_amdgcn_mfma_f32_16x16x32_bf16(a[fm], b[nf], acc[fm][nf], 0, 0, 0);
    }
    if (t + 1 < KT) {
      __builtin_amdgcn_s_barrier();
      STAGE(t + 1);
      asm volatile("s_waitcnt vmcnt(0)" ::: "memory");
      __builtin_amdgcn_s_barrier();
    }
  }
#undef STAGE
  __syncthreads();

  // fused expert-blend epilogue (coeff transposed [8][132]: conflict-free)
  float* cl2 = (float*)lds;
  float* tb  = (float*)(lds + 4352);
  {
#pragma unroll
    for (int i = 0; i < 2; ++i) {
      int idx = i * 512 + tid;
      int e = idx & 7, n = idx >> 3;
      cl2[e * 132 + n] = coeff[((size_t)bx * 128 + n) * 8 + e];
    }
  }
  __syncthreads();
  const int e0 = lane & 1;
  const int o_loc = (wc << 3) + (l15 >> 1);

  if (MODE == 0) {
    float bb[4];
#pragma unroll
    for (int fn = 0; fn < 4; ++fn) bb[fn] = bias[(fn * 2 + e0) * 512 + by * 32 + o_loc];
#pragma unroll
    for (int fm = 0; fm < 4; ++fm) {
#pragma unroll
      for (int r2 = 0; r2 < 4; ++r2) {
        int n_loc = (wr << 6) + fm * 16 + (lg << 2) + r2;
        float s = 0.f;
#pragma unroll
        for (int fn = 0; fn < 4; ++fn)
          s += cl2[(fn * 2 + e0) * 132 + n_loc] * (acc[fm][fn][r2] + bb[fn]);
        s += __shfl_xor(s, 1);
        s = s > 0.f ? s : expm1f(s);
        if ((lane & 1) == (fm & 1)) tb[n_loc * 33 + o_loc] = s;
      }
    }
    __syncthreads();
    {
      int n_loc = tid & 127, c = tid >> 7;
      const float* p = &tb[n_loc * 33 + c * 8];
      bf16x8 v;
#pragma unroll
      for (int j = 0; j < 8; ++j) v[j] = (__bf16)p[j];
      size_t off = (((size_t)(bx >> 1) * KTD + (by >> 1)) * 2 + (by & 1)) * 16384
                 + (size_t)c * 4096 + (size_t)((bx & 1) * 128 + n_loc) * 16;
      *(bf16x8*)((char*)dstS + off) = v;
    }
  } else {
    const int o_g = by * 32 + o_loc;
    if (o_g < 171) {
      float bb[4];
#pragma unroll
      for (int fn = 0; fn < 4; ++fn) bb[fn] = bias[(fn * 2 + e0) * 171 + o_g];
#pragma unroll
      for (int fm = 0; fm < 4; ++fm) {
#pragma unroll
        for (int r2 = 0; r2 < 4; ++r2) {
          int n_loc = (wr << 6) + fm * 16 + (lg << 2) + r2;
          float s = 0.f;
#pragma unroll
          for (int fn = 0; fn < 4; ++fn)
            s += cl2[(fn * 2 + e0) * 132 + n_loc] * (acc[fm][fn][r2] + bb[fn]);
          s += __shfl_xor(s, 1);
          if ((lane & 1) == (fm & 1))
            dstF[(size_t)(bx * 128 + n_loc) * 171 + o_g] = s;
        }
      }
    }
  }
}

// ---------------- launch ----------------
extern "C" void kernel_launch(void* const* d_in, const int* in_sizes, int n_in,
                              void* d_out, int out_size, void* d_ws, size_t ws_size,
                              hipStream_t stream)
{
  const float* latent    = (const float*)d_in[0];
  const float* condition = (const float*)d_in[1];
  const float* phase     = (const float*)d_in[2];
  const float* gw1 = (const float*)d_in[3];
  const float* gb1 = (const float*)d_in[4];
  const float* gw2 = (const float*)d_in[5];
  const float* gb2 = (const float*)d_in[6];
  const float* gw3 = (const float*)d_in[7];
  const float* gb3 = (const float*)d_in[8];
  const float* w0  = (const float*)d_in[9];
  const float* b0  = (const float*)d_in[10];
  const float* w1  = (const float*)d_in[11];
  const float* b1  = (const float*)d_in[12];
  const float* w2  = (const float*)d_in[13];
  const float* b2  = (const float*)d_in[14];

  float* out   = (float*)d_out;
  float* coeff = out + (size_t)NR * 171;

  char* ws = (char*)d_ws;
  __hip_bfloat16* x0s = (__hip_bfloat16*)ws; ws += (size_t)16 * 5 * 32768;
  __hip_bfloat16* x1s = (__hip_bfloat16*)ws; ws += (size_t)16 * 9 * 32768;
  __hip_bfloat16* x2s = (__hip_bfloat16*)ws; ws += (size_t)16 * 8 * 32768;
  __hip_bfloat16* w0s = (__hip_bfloat16*)ws; ws += (size_t)16 * 5 * 32768;
  __hip_bfloat16* w1s = (__hip_bfloat16*)ws; ws += (size_t)16 * 9 * 32768;
  __hip_bfloat16* w2s = (__hip_bfloat16*)ws; ws += (size_t)6 * 8 * 32768;

  // K1: fused prep — gate (256) + w1/w0/w2 (544) + x0 coalesced (128) + x1 (64)
  prepG<<<992, 256, 0, stream>>>(latent, condition, phase,
                                 gw1, gb1, gw2, gb2, gw3, gb3,
                                 w0, w1, w2,
                                 x0s, x1s, w0s, w1s, w2s, coeff);

  // K2-K4: 128x256-tile fused GEMMs, rectangular XCD-L2 tile mapping
  gemm_k<5, 9, 0, 8><<<512, 512, 0, stream>>>(x0s, w0s, coeff, b0, x1s, nullptr);
  gemm_k<9, 8, 0, 8><<<512, 512, 0, stream>>>(x1s, w1s, coeff, b1, x2s, nullptr);
  gemm_k<8, 0, 1, 3><<<192, 512, 0, stream>>>(x2s, w2s, coeff, b2, nullptr, out);
}

// Round 20
// 70.155 us; speedup vs baseline: 4.4102x; 1.0369x over previous
//
#include <hip/hip_runtime.h>
#include <hip/hip_bf16.h>

#define NR 4096

typedef float f32x4 __attribute__((ext_vector_type(4)));
typedef __bf16 bf16x8 __attribute__((ext_vector_type(8)));

typedef __attribute__((address_space(1))) unsigned int u32_g;
typedef __attribute__((address_space(3))) unsigned int u32_l;

__device__ __forceinline__ void gl_lds16(const void* g, void* l) {
  __builtin_amdgcn_global_load_lds((const u32_g*)g, (u32_l*)l, 16, 0, 0);
}

// =====================================================================
// Staged operand layout (bf16): logical Z[rows][K], row-blocks RB of 256,
// K-tiles T of 64:  chunk(row,k) at
//   off = ((RB*KT + T)*2 + s)*16384 + g*4096 + (row&255)*16 + e*2
// B cols expert-interleaved: p = (o>>5)*256+((o>>3)&3)*64+(e>>1)*16+(o&7)*2+(e&1)
// =====================================================================

// ---- w-stager v3: two-pass halves ([128][33] f32 = 16.9KB LDS) ----
// Pass h covers experts 4h..4h+3; loads coalesced, stores 512B runs.
__device__ void wstage2p(const float* __restrict__ w, __hip_bfloat16* __restrict__ out,
                         int Kin, int KT, int Oin, int u, char* LDS)
{
  int ob = u / (KT * 2);
  int rem = u - ob * (KT * 2);
  int T = rem >> 1, s = rem & 1;
  float* t = (float*)LDS;                    // [128][33]
  const int tid = threadIdx.x;
  const int kbase = T * 64 + s * 32;
  const size_t segbase = (((size_t)ob * KT + T) * 2 + s) * 16384;

#pragma unroll 1
  for (int h = 0; h < 2; ++h) {
    // load half-tile: 128 rows (4 experts x 32 k) x 32 cols
    if (Oin == 512) {
#pragma unroll
      for (int i = 0; i < 4; ++i) {
        int idx = i * 256 + tid;             // 1024 float4
        int row = idx >> 3, c4 = idx & 7;
        int e = h * 4 + (row >> 5), kk = row & 31;
        int k = kbase + kk;
        float4 v = {0.f, 0.f, 0.f, 0.f};
        if (k < Kin) v = *(const float4*)&w[((size_t)e * Kin + k) * 512 + ob * 32 + c4 * 4];
        t[row * 33 + c4 * 4 + 0] = v.x;
        t[row * 33 + c4 * 4 + 1] = v.y;
        t[row * 33 + c4 * 4 + 2] = v.z;
        t[row * 33 + c4 * 4 + 3] = v.w;
      }
    } else {
#pragma unroll
      for (int i = 0; i < 4; ++i) {
        int idx = i * 256 + tid;
        int row = idx >> 3, c4 = idx & 7;
        int e = h * 4 + (row >> 5), kk = row & 31;
        int k = kbase + kk;
#pragma unroll
        for (int j = 0; j < 4; ++j) {
          int o = ob * 32 + c4 * 4 + j;
          float f = (k < Kin && o < Oin) ? w[((size_t)e * Kin + k) * (size_t)Oin + o] : 0.f;
          t[row * 33 + c4 * 4 + j] = f;
        }
      }
    }
    __syncthreads();
    if (tid < 128) {
      int p = ((tid >> 5) << 6) | (h << 5) | (tid & 31);  // all p with bit5==h
      int e = ((p >> 4) & 3) * 2 + (p & 1);
      int oo = ((p >> 6) & 3) * 8 + ((p >> 1) & 7);
#pragma unroll
      for (int g = 0; g < 4; ++g) {
        bf16x8 v;
#pragma unroll
        for (int e8 = 0; e8 < 8; ++e8)
          v[e8] = (__bf16)t[((e & 3) * 32 + g * 8 + e8) * 33 + oo];
        *(bf16x8*)((char*)out + segbase + g * 4096 + (size_t)p * 16) = v;
      }
    }
    __syncthreads();
  }
}

// ---- x0 stager v3: 16 rows/block, 18.3KB LDS, coalesced both sides ----
__device__ void x0stage16(int u, const float* __restrict__ cond, const float* __restrict__ lat,
                          __hip_bfloat16* __restrict__ out, char* LDS)
{
  float* Lc = (float*)LDS;            // [16][221] f32
  float* Ll = (float*)(LDS + 14144);  // [16][65] f32
  const int tid = threadIdx.x;
  const int n0 = u * 16;

  for (int i = tid; i < 16 * 219; i += 256) {
    int r = i / 219, c = i - r * 219;
    Lc[r * 221 + c] = cond[(size_t)n0 * 219 + i];
  }
  for (int i = tid; i < 16 * 64; i += 256) {
    int r = i >> 6, c = i & 63;
    Ll[r * 65 + c] = lat[(size_t)n0 * 64 + i];
  }
  __syncthreads();

  const int RB = u >> 4;
  const int rbase = (u & 15) * 16;
#pragma unroll
  for (int ii = 0; ii < 3; ++ii) {
    int cc = ii * 256 + tid;                       // 640 chunks: kc*16 + row
    if (cc < 640) {
      int row = cc & 15, kc = cc >> 4;             // kc in 0..39
      int T = kc >> 3, s = (kc >> 2) & 1, g = kc & 3;
      bf16x8 v;
#pragma unroll
      for (int j = 0; j < 8; ++j) {
        int k = kc * 8 + j;
        float f = (k < 219) ? Lc[row * 221 + k]
                : (k < 283) ? Ll[row * 65 + (k - 219)] : 0.f;
        v[j] = (__bf16)f;
      }
      size_t off = (((size_t)RB * 5 + T) * 2 + s) * 16384 + (size_t)g * 4096
                 + (size_t)(rbase + row) * 16;
      *(bf16x8*)((char*)out + off) = v;
    }
  }
}

// ---- x1 latent stager (R19-verified): 64 rows/block, 16.6KB ----
__device__ void x1stage64(int u, const float* __restrict__ lat,
                          __hip_bfloat16* __restrict__ out, char* LDS)
{
  float* L = (float*)LDS;  // [64][65] f32
  const int tid = threadIdx.x;
  const int n0 = u * 64;
  for (int i = tid; i < 64 * 64; i += 256) {
    int r = i >> 6, c = i & 63;
    L[r * 65 + c] = lat[(size_t)n0 * 64 + i];
  }
  __syncthreads();
  const int RB = u >> 2;
  const int rbase = (u & 3) * 64;
#pragma unroll
  for (int ii = 0; ii < 2; ++ii) {
    int cc = ii * 256 + tid;
    int row = cc & 63, kc = cc >> 6;
    int s = kc >> 2, g = kc & 3;
    bf16x8 v;
#pragma unroll
    for (int j = 0; j < 8; ++j) v[j] = (__bf16)L[row * 65 + kc * 8 + j];
    size_t off = ((size_t)RB * 9 + 8) * 32768
               + (size_t)((s << 10) | (g << 8) | (rbase + row)) * 16;
    *(bf16x8*)((char*)out + off) = v;
  }
}

// ---- gate8: 8 rows/block x 512 blocks; f32x4 LDS reads; 12.3KB LDS ----
// Per-output accumulation = k-ascending independent chain (f32x4 lanes) ->
// coeff bit-identical to all prior rounds.
__device__ void gate8(int gb, const float* __restrict__ phs, const float* __restrict__ lat,
                      const float* __restrict__ gw1, const float* __restrict__ gb1,
                      const float* __restrict__ gw2, const float* __restrict__ gb2,
                      const float* __restrict__ gw3, const float* __restrict__ gb3,
                      float* __restrict__ coeff, char* LDS)
{
  float* aT  = (float*)LDS;           // [128][8] f32: g0T, later h2T (4096B)
  float* h1T = (float*)(LDS + 4096);  // [128][8]
  float* w3L = (float*)(LDS + 8192);  // [128][8]
  const int tid = threadIdx.x;
  const int n0 = gb * 8;

  for (int i = tid; i < 104 * 8; i += 256) {
    int k = i >> 3, r = i & 7;
    aT[i] = (k < 40) ? phs[(size_t)(n0 + r) * 40 + k]
                     : lat[(size_t)(n0 + r) * 64 + (k - 40)];
  }
  ((float4*)w3L)[tid] = ((const float4*)gw3)[tid];
  __syncthreads();

  const int col = tid & 127, rh = tid >> 7;  // rh in {0,1}: rows rh*4..rh*4+3
  // layer 1
  {
    f32x4 acc = {};
#pragma unroll 8
    for (int k = 0; k < 104; ++k) {
      float w = gw1[k * 128 + col];
      f32x4 g4 = *(const f32x4*)&aT[k * 8 + rh * 4];
      acc += g4 * w;
    }
    float bb = gb1[col];
    f32x4 v = acc + bb;
#pragma unroll
    for (int j = 0; j < 4; ++j) v[j] = v[j] > 0.f ? v[j] : expm1f(v[j]);
    *(f32x4*)&h1T[col * 8 + rh * 4] = v;
  }
  __syncthreads();
  // layer 2
  {
    f32x4 acc = {};
#pragma unroll 8
    for (int k = 0; k < 128; ++k) {
      float w = gw2[k * 128 + col];
      f32x4 g4 = *(const f32x4*)&h1T[k * 8 + rh * 4];
      acc += g4 * w;
    }
    float bb = gb2[col];
    f32x4 v = acc + bb;
#pragma unroll
    for (int j = 0; j < 4; ++j) v[j] = v[j] > 0.f ? v[j] : expm1f(v[j]);
    *(f32x4*)&aT[col * 8 + rh * 4] = v;
  }
  __syncthreads();
  // layer 3 + softmax (lanes 0..63: row=tid>>3, e=tid&7)
  if (tid < 64) {
    int row = tid >> 3, e = tid & 7;
    float a3 = 0.f;
#pragma unroll 8
    for (int k = 0; k < 128; ++k) a3 += aT[k * 8 + row] * w3L[k * 8 + e];
    float lgt = a3 + gb3[e];
    float m = lgt;
    m = fmaxf(m, __shfl_xor(m, 1));
    m = fmaxf(m, __shfl_xor(m, 2));
    m = fmaxf(m, __shfl_xor(m, 4));
    float ex = expf(lgt - m);
    float s = ex;
    s += __shfl_xor(s, 1);
    s += __shfl_xor(s, 2);
    s += __shfl_xor(s, 4);
    coeff[(size_t)(n0 + row) * 8 + e] = ex / s;
  }
}

// ---- prepG: gate (512, first) + stagers, 18.4KB LDS -> 8 blocks/CU ----
__global__ __launch_bounds__(256) void prepG(
    const float* __restrict__ latent, const float* __restrict__ condition,
    const float* __restrict__ phase,
    const float* __restrict__ gw1, const float* __restrict__ gb1,
    const float* __restrict__ gw2, const float* __restrict__ gb2,
    const float* __restrict__ gw3, const float* __restrict__ gb3,
    const float* __restrict__ w0, const float* __restrict__ w1, const float* __restrict__ w2,
    __hip_bfloat16* x0s, __hip_bfloat16* x1s,
    __hip_bfloat16* w0s, __hip_bfloat16* w1s, __hip_bfloat16* w2s,
    float* coeff)
{
  __shared__ __align__(16) char LDS[18432];
  int b = blockIdx.x;
  if (b < 512) {
    gate8(b, phase, latent, gw1, gb1, gw2, gb2, gw3, gb3, coeff, LDS);
    return;
  }
  b -= 512;
  if (b < 288)       wstage2p(w1, w1s, 576, 9, 512, b, LDS);          // 288
  else if (b < 448)  wstage2p(w0, w0s, 283, 5, 512, b - 288, LDS);    // 160
  else if (b < 544)  wstage2p(w2, w2s, 512, 8, 171, b - 448, LDS);    // 96
  else if (b < 800)  x0stage16(b - 544, condition, latent, x0s, LDS); // 256
  else               x1stage64(b - 800, latent, x1s, LDS);            // 64
}

// =====================================================================
// GEMM: 128x256 tile, 48KB LDS single-buffer, 2 blocks/CU, rectangular
// per-XCD tile mapping (R13-verified). MODE 0 -> staged bf16; 1 -> fp32.
// =====================================================================
template <int KT, int KTD, int MODE, int BYPG>
__global__ __launch_bounds__(512, 4) void gemm_k(
    const __hip_bfloat16* __restrict__ Ap, const __hip_bfloat16* __restrict__ Bp,
    const float* __restrict__ coeff, const float* __restrict__ bias,
    __hip_bfloat16* __restrict__ dstS, float* __restrict__ dstF)
{
  __shared__ __align__(16) char lds[49152];
  const int bid = blockIdx.x;
  const int xcd = bid & 7, r = bid >> 3;
  const int bx = ((xcd & 3) << 3) + (r & 7);
  const int by = (xcd >> 2) * BYPG + (r >> 3);
  const int tid = threadIdx.x;
  const int lane = tid & 63;
  const int wid = tid >> 6;
  const int wr = wid >> 2, wc = wid & 3;
  const int l15 = lane & 15, lg = lane >> 4;
  const int aHalf = (bx & 1) * 2048;

  const char* aG = (const char*)Ap + (size_t)(bx >> 1) * KT * 32768;
  const char* bG = (const char*)Bp + (size_t)by * KT * 32768;

#define STAGE(T)                                                             \
  {                                                                          \
    const char* gA_ = aG + (size_t)(T) * 32768;                              \
    const char* gB_ = bG + (size_t)(T) * 32768;                              \
    _Pragma("unroll") for (int i = 0; i < 2; ++i) {                          \
      int c = i * 512 + tid;                                                 \
      gl_lds16(gA_ + (c >> 9) * 16384 + ((c >> 7) & 3) * 4096 + aHalf        \
                   + (c & 127) * 16,                                         \
               lds + c * 16);                                                \
    }                                                                        \
    _Pragma("unroll") for (int i = 0; i < 4; ++i) {                          \
      int c = i * 512 + tid;                                                 \
      gl_lds16(gB_ + c * 16, lds + 16384 + c * 16);                          \
    }                                                                        \
  }

  f32x4 acc[4][4] = {};

  STAGE(0);
  asm volatile("s_waitcnt vmcnt(0)" ::: "memory");
  __builtin_amdgcn_s_barrier();

#pragma unroll 1
  for (int t = 0; t < KT; ++t) {
#pragma unroll
    for (int s = 0; s < 2; ++s) {
      bf16x8 a[4], b[4];
#pragma unroll
      for (int fm = 0; fm < 4; ++fm)
        a[fm] = *(const bf16x8*)(lds + s * 8192 + lg * 2048
                                 + ((wr << 6) + fm * 16 + l15) * 16);
#pragma unroll
      for (int nf = 0; nf < 4; ++nf)
        b[nf] = *(const bf16x8*)(lds + 16384 + s * 16384 + lg * 4096
                                 + (wc << 10) + nf * 256 + l15 * 16);
#pragma unroll
      for (int fm = 0; fm < 4; ++fm)
#pragma unroll
        for (int nf = 0; nf < 4; ++nf)
          acc[fm][nf] = __builtin_amdgcn_mfma_f32_16x16x32_bf16(a[fm], b[nf], acc[fm][nf], 0, 0, 0);
    }
    if (t + 1 < KT) {
      __builtin_amdgcn_s_barrier();
      STAGE(t + 1);
      asm volatile("s_waitcnt vmcnt(0)" ::: "memory");
      __builtin_amdgcn_s_barrier();
    }
  }
#undef STAGE
  __syncthreads();

  // fused expert-blend epilogue (coeff transposed [8][132]: conflict-free)
  float* cl2 = (float*)lds;
  float* tb  = (float*)(lds + 4352);
  {
#pragma unroll
    for (int i = 0; i < 2; ++i) {
      int idx = i * 512 + tid;
      int e = idx & 7, n = idx >> 3;
      cl2[e * 132 + n] = coeff[((size_t)bx * 128 + n) * 8 + e];
    }
  }
  __syncthreads();
  const int e0 = lane & 1;
  const int o_loc = (wc << 3) + (l15 >> 1);

  if (MODE == 0) {
    float bb[4];
#pragma unroll
    for (int fn = 0; fn < 4; ++fn) bb[fn] = bias[(fn * 2 + e0) * 512 + by * 32 + o_loc];
#pragma unroll
    for (int fm = 0; fm < 4; ++fm) {
#pragma unroll
      for (int r2 = 0; r2 < 4; ++r2) {
        int n_loc = (wr << 6) + fm * 16 + (lg << 2) + r2;
        float s = 0.f;
#pragma unroll
        for (int fn = 0; fn < 4; ++fn)
          s += cl2[(fn * 2 + e0) * 132 + n_loc] * (acc[fm][fn][r2] + bb[fn]);
        s += __shfl_xor(s, 1);
        s = s > 0.f ? s : expm1f(s);
        if ((lane & 1) == (fm & 1)) tb[n_loc * 33 + o_loc] = s;
      }
    }
    __syncthreads();
    {
      int n_loc = tid & 127, c = tid >> 7;
      const float* p = &tb[n_loc * 33 + c * 8];
      bf16x8 v;
#pragma unroll
      for (int j = 0; j < 8; ++j) v[j] = (__bf16)p[j];
      size_t off = (((size_t)(bx >> 1) * KTD + (by >> 1)) * 2 + (by & 1)) * 16384
                 + (size_t)c * 4096 + (size_t)((bx & 1) * 128 + n_loc) * 16;
      *(bf16x8*)((char*)dstS + off) = v;
    }
  } else {
    const int o_g = by * 32 + o_loc;
    if (o_g < 171) {
      float bb[4];
#pragma unroll
      for (int fn = 0; fn < 4; ++fn) bb[fn] = bias[(fn * 2 + e0) * 171 + o_g];
#pragma unroll
      for (int fm = 0; fm < 4; ++fm) {
#pragma unroll
        for (int r2 = 0; r2 < 4; ++r2) {
          int n_loc = (wr << 6) + fm * 16 + (lg << 2) + r2;
          float s = 0.f;
#pragma unroll
          for (int fn = 0; fn < 4; ++fn)
            s += cl2[(fn * 2 + e0) * 132 + n_loc] * (acc[fm][fn][r2] + bb[fn]);
          s += __shfl_xor(s, 1);
          if ((lane & 1) == (fm & 1))
            dstF[(size_t)(bx * 128 + n_loc) * 171 + o_g] = s;
        }
      }
    }
  }
}

// ---------------- launch ----------------
extern "C" void kernel_launch(void* const* d_in, const int* in_sizes, int n_in,
                              void* d_out, int out_size, void* d_ws, size_t ws_size,
                              hipStream_t stream)
{
  const float* latent    = (const float*)d_in[0];
  const float* condition = (const float*)d_in[1];
  const float* phase     = (const float*)d_in[2];
  const float* gw1 = (const float*)d_in[3];
  const float* gb1 = (const float*)d_in[4];
  const float* gw2 = (const float*)d_in[5];
  const float* gb2 = (const float*)d_in[6];
  const float* gw3 = (const float*)d_in[7];
  const float* gb3 = (const float*)d_in[8];
  const float* w0  = (const float*)d_in[9];
  const float* b0  = (const float*)d_in[10];
  const float* w1  = (const float*)d_in[11];
  const float* b1  = (const float*)d_in[12];
  const float* w2  = (const float*)d_in[13];
  const float* b2  = (const float*)d_in[14];

  float* out   = (float*)d_out;
  float* coeff = out + (size_t)NR * 171;

  char* ws = (char*)d_ws;
  __hip_bfloat16* x0s = (__hip_bfloat16*)ws; ws += (size_t)16 * 5 * 32768;
  __hip_bfloat16* x1s = (__hip_bfloat16*)ws; ws += (size_t)16 * 9 * 32768;
  __hip_bfloat16* x2s = (__hip_bfloat16*)ws; ws += (size_t)16 * 8 * 32768;
  __hip_bfloat16* w0s = (__hip_bfloat16*)ws; ws += (size_t)16 * 5 * 32768;
  __hip_bfloat16* w1s = (__hip_bfloat16*)ws; ws += (size_t)16 * 9 * 32768;
  __hip_bfloat16* w2s = (__hip_bfloat16*)ws; ws += (size_t)6 * 8 * 32768;

  // K1: fused prep — gate8 (512) + w stagers (544) + x0 (256) + x1 (64)
  prepG<<<1376, 256, 0, stream>>>(latent, condition, phase,
                                  gw1, gb1, gw2, gb2, gw3, gb3,
                                  w0, w1, w2,
                                  x0s, x1s, w0s, w1s, w2s, coeff);

  // K2-K4: 128x256-tile fused GEMMs, rectangular XCD-L2 tile mapping
  gemm_k<5, 9, 0, 8><<<512, 512, 0, stream>>>(x0s, w0s, coeff, b0, x1s, nullptr);
  gemm_k<9, 8, 0, 8><<<512, 512, 0, stream>>>(x1s, w1s, coeff, b1, x2s, nullptr);
  gemm_k<8, 0, 1, 3><<<192, 512, 0, stream>>>(x2s, w2s, coeff, b2, nullptr, out);
}